// Round 1
// baseline (107.224 us; speedup 1.0000x reference)
//
#include <hip/hip_runtime.h>
#include <math.h>

// Problem constants
constexpr int kB = 2;
constexpr int kC = 128;
constexpr int kN = 784;
constexpr float kInvT = 1.0f / 11.313708498984761f;  // 1/sqrt(C)
constexpr float kInvC = 1.0f / 128.0f;

constexpr size_t kOutElems  = (size_t)kB * kC * kN;  // 200704
constexpr size_t kAttnElems = (size_t)kB * kN * kN;  // 1229312

__device__ inline float wave_max(float v) {
#pragma unroll
    for (int o = 32; o > 0; o >>= 1) v = fmaxf(v, __shfl_xor(v, o, 64));
    return v;
}
__device__ inline float wave_sum(float v) {
#pragma unroll
    for (int o = 32; o > 0; o >>= 1) v += __shfl_xor(v, o, 64);
    return v;
}

// ================= Kernel 1: D[b,k,q] = sum_c |q[c,q]/T - k[c,k]| (raw sums) =================
// 64k x 64q tile, 4k x 4q per thread (16 indep accs; VALU:LDS = 64:24 cyc/c-iter),
// c split in 2 halves. LDS 34.8 KB -> 4 blocks/CU resident; grid 2b*2ch*13*13 = 676.
// k-operand: b128 16-lane broadcast; q-operand: b128 2-way (free). Half 0 -> attn
// region, half 1 -> ws; softmax sums the halves.
constexpr int TK = 64;
constexpr int TQ = 64;
constexpr int NKT = (kN + TK - 1) / TK;  // 13
constexpr int NQT = (kN + TQ - 1) / TQ;  // 13
constexpr int CSP = 2;
constexpr int CH = kC / CSP;             // 64
constexpr int DSTR = 68;                 // 64+4 pad

template <bool USE_WS>
__global__ __launch_bounds__(256) void dist_kernel(const float* __restrict__ qg,
                                                   const float* __restrict__ kg,
                                                   float* __restrict__ D0,
                                                   float* __restrict__ D1) {
    int bid = blockIdx.x;
    const int qt = bid % NQT; bid /= NQT;
    const int kt = bid % NKT; bid /= NKT;
    const int ch = bid & 1;   bid >>= 1;
    const int b  = bid;
    const int k0 = kt * TK;
    const int q0 = qt * TQ;
    const int t  = threadIdx.x;

    __shared__ float ks[CH][DSTR];  // 17.4 KB
    __shared__ float qs[CH][DSTR];  // 17.4 KB

    const float* kb = kg + ((size_t)b * kC + ch * CH) * kN;
    const float* qb = qg + ((size_t)b * kC + ch * CH) * kN;

    // Stage both 64x64 tiles: 64 rows x 16 float4 each (4 iters per array).
#pragma unroll
    for (int i = t; i < CH * 16; i += 256) {
        const int c  = i >> 4;
        const int x4 = (i & 15) << 2;
        *reinterpret_cast<float4*>(&ks[c][x4]) =
            *reinterpret_cast<const float4*>(kb + (size_t)c * kN + min(k0 + x4, kN - 4));
        float4 qv = *reinterpret_cast<const float4*>(qb + (size_t)c * kN + min(q0 + x4, kN - 4));
        qv.x *= kInvT; qv.y *= kInvT; qv.z *= kInvT; qv.w *= kInvT;
        *reinterpret_cast<float4*>(&qs[c][x4]) = qv;
    }
    __syncthreads();

    const int qx = (t & 15) << 2;  // 16 q-groups (b128, 2-way across half-wave = free)
    const int kx = (t >> 4) << 2;  // 16 k-groups (b128, 16-lane broadcast)

    float acc[4][4];
#pragma unroll
    for (int i = 0; i < 4; ++i)
#pragma unroll
        for (int j = 0; j < 4; ++j) acc[i][j] = 0.0f;

#pragma unroll 4
    for (int c = 0; c < CH; ++c) {
        const float4 kv = *reinterpret_cast<const float4*>(&ks[c][kx]);
        const float4 qv = *reinterpret_cast<const float4*>(&qs[c][qx]);
        const float kf[4] = {kv.x, kv.y, kv.z, kv.w};
        const float qf[4] = {qv.x, qv.y, qv.z, qv.w};
#pragma unroll
        for (int i = 0; i < 4; ++i)
#pragma unroll
            for (int j = 0; j < 4; ++j)
                acc[i][j] += fabsf(qf[j] - kf[i]);  // v_sub + v_add(abs) = 2 VALU
    }

    const int qcol = q0 + qx;
    if (qcol < kN) {
        float* dst = (USE_WS && ch) ? D1 : D0;
#pragma unroll
        for (int i = 0; i < 4; ++i) {
            const int krow = k0 + kx + i;
            if (krow < kN) {
                const size_t off = ((size_t)b * kN + krow) * kN + qcol;
                if (USE_WS) {
                    *reinterpret_cast<float4*>(dst + off) =
                        make_float4(acc[i][0], acc[i][1], acc[i][2], acc[i][3]);
                } else {
                    atomicAdd(&D0[off + 0], acc[i][0]);
                    atomicAdd(&D0[off + 1], acc[i][1]);
                    atomicAdd(&D0[off + 2], acc[i][2]);
                    atomicAdd(&D0[off + 3], acc[i][3]);
                }
            }
        }
    }
}

// ================= Kernel 2: row softmax over q (sums the two c-halves) =================
template <bool SUM2>
__global__ __launch_bounds__(256) void softmax_kernel(float* __restrict__ A,
                                                      const float* __restrict__ W) {
    const size_t row = (size_t)blockIdx.x * kN;
    float4* A4 = reinterpret_cast<float4*>(A + row);
    const float4* W4 = reinterpret_cast<const float4*>(W + row);
    const int t = threadIdx.x;
    const int lane = t & 63, wid = t >> 6;
    const bool act = t < (kN / 4);  // 196
    __shared__ float xred[4];

    float4 x = make_float4(-1e30f, -1e30f, -1e30f, -1e30f);
    if (act) {
        x = A4[t];
        if (SUM2) {
            const float4 w = W4[t];
            x.x += w.x; x.y += w.y; x.z += w.z; x.w += w.w;
        }
    }

    float m = fmaxf(fmaxf(x.x, x.y), fmaxf(x.z, x.w));
    m = wave_max(m);
    if (lane == 0) xred[wid] = m;
    __syncthreads();
    m = fmaxf(fmaxf(xred[0], xred[1]), fmaxf(xred[2], xred[3]));
    __syncthreads();

    float4 p;
    p.x = __expf((x.x - m) * kInvC);
    p.y = __expf((x.y - m) * kInvC);
    p.z = __expf((x.z - m) * kInvC);
    p.w = __expf((x.w - m) * kInvC);
    float lsum = p.x + p.y + p.z + p.w;  // inactive: exp(-huge)=0
    lsum = wave_sum(lsum);
    if (lane == 0) xred[wid] = lsum;
    __syncthreads();
    const float inv = 1.0f / (xred[0] + xred[1] + xred[2] + xred[3]);
    if (act) {
        p.x *= inv; p.y *= inv; p.z *= inv; p.w *= inv;
        A4[t] = p;
    }
}

// ================= Kernel 3: out[b,c,k] = sum_q v[b,c,q]*attn[b,k,q] via fp16 MFMA ==========
// GEMM shape per batch: M=128(c), N=784(k), K=784(q). out = V * A^T.
// Block = 64c x 64k tile, full K in 7 chunks of 128 q staged in LDS as fp16
// (inline fp32->fp16 RTN convert; v,attn in [-6,6]/[0,1] => fp16 rel err 2^-11,
// out error ~1e-4 absmax). Grid = 2b * 2ct * 13kt = 52 blocks. 4 waves, each
// owns 16 c-rows x 64 k-cols = 1x4 mfma_f32_16x16x32_f16 frags (acc 16 VGPR).
// Next chunk's 16 float4 global loads are register-prefetched during MFMA.
// Fragment map (m89-verified, dtype-independent): A row=lane&15, k=(lane>>4)*8+j;
// B col=lane&15, same k; D col=lane&15, row=(lane>>4)*4+reg.
typedef _Float16 half4v __attribute__((ext_vector_type(4)));
typedef _Float16 half8v __attribute__((ext_vector_type(8)));
typedef float f32x4 __attribute__((ext_vector_type(4)));

constexpr int GM = 64;                    // c rows per block
constexpr int GN = 64;                    // k cols per block
constexpr int GK = 128;                   // q per chunk
constexpr int NCH = (kN + GK - 1) / GK;   // 7 (last chunk: 16 valid q, zero-padded)
constexpr int NKT3 = (kN + GN - 1) / GN;  // 13
constexpr int LSTR = 136;                 // fp16 row stride: 128 + 8 pad (272 B, 2-way banks)

__global__ __launch_bounds__(256) void bmm_mfma(const float* __restrict__ vg,
                                                const float* __restrict__ attn,
                                                float* __restrict__ out) {
    int bid = blockIdx.x;
    const int kt = bid % NKT3; bid /= NKT3;
    const int ct = bid & 1;    bid >>= 1;
    const int b  = bid;
    const int k0 = kt * GN;
    const int c0 = ct * GM;
    const int t  = threadIdx.x;
    const int lane = t & 63;
    const int w = t >> 6;

    __shared__ _Float16 vs[GM][LSTR];   // 17.4 KB  (A operand: V tile)
    __shared__ _Float16 as_[GN][LSTR];  // 17.4 KB  (B operand: attn tile)

    const float* vb = vg + ((size_t)b * kC + c0) * kN;
    const float* ab = attn + (size_t)b * kN * kN;

    // Staging map: linear idx = t + 256*i over 64rows x 32 float4-cols.
    const int col4 = t & 31;        // fixed per thread -> fully coalesced 512B rows
    const int rb   = t >> 5;        // row base 0..7, rows rb + 8*i

    float4 pv[8], pa[8];

    auto load_chunk = [&](int chnk) {
        const int qv = chnk * GK + 4 * col4;
        const bool qok = qv < kN;   // kN%4==0: float4 fully valid or fully out
#pragma unroll
        for (int i = 0; i < 8; ++i) {
            const int row = rb + 8 * i;
            pv[i] = qok ? *reinterpret_cast<const float4*>(vb + (size_t)row * kN + qv)
                        : make_float4(0.f, 0.f, 0.f, 0.f);
            const int krow = k0 + row;
            pa[i] = (qok && krow < kN)
                        ? *reinterpret_cast<const float4*>(ab + (size_t)krow * kN + qv)
                        : make_float4(0.f, 0.f, 0.f, 0.f);
        }
    };

    auto store_chunk = [&]() {
        const int col = 4 * col4;
#pragma unroll
        for (int i = 0; i < 8; ++i) {
            const int row = rb + 8 * i;
            half4v hv = {(_Float16)pv[i].x, (_Float16)pv[i].y,
                         (_Float16)pv[i].z, (_Float16)pv[i].w};
            *reinterpret_cast<half4v*>(&vs[row][col]) = hv;
            half4v ha = {(_Float16)pa[i].x, (_Float16)pa[i].y,
                         (_Float16)pa[i].z, (_Float16)pa[i].w};
            *reinterpret_cast<half4v*>(&as_[row][col]) = ha;
        }
    };

    f32x4 acc[4] = {};  // 4 n-frags (wave: 16 c-rows x 64 k-cols)

    const int arow = 16 * w + (lane & 15);   // A row in vs
    const int brow0 = lane & 15;             // B row base in as_
    const int kgrp = (lane >> 4) * 8;        // k offset within 32-step

    load_chunk(0);
    for (int chnk = 0; chnk < NCH; ++chnk) {
        __syncthreads();   // previous chunk's readers done
        store_chunk();
        __syncthreads();
        if (chnk + 1 < NCH) load_chunk(chnk + 1);  // VMEM overlaps MFMA below

#pragma unroll
        for (int ks = 0; ks < GK / 32; ++ks) {
            const int koff = ks * 32 + kgrp;
            const half8v av = *reinterpret_cast<const half8v*>(&vs[arow][koff]);
#pragma unroll
            for (int n = 0; n < 4; ++n) {
                const half8v bv =
                    *reinterpret_cast<const half8v*>(&as_[16 * n + brow0][koff]);
                acc[n] = __builtin_amdgcn_mfma_f32_16x16x32_f16(av, bv, acc[n], 0, 0, 0);
            }
        }
    }

    // Epilogue: D col = lane&15, row = (lane>>4)*4 + r.
    const int crow = c0 + 16 * w + (lane >> 4) * 4;
    const int kc = k0 + (lane & 15);
#pragma unroll
    for (int n = 0; n < 4; ++n) {
        const int kcol = kc + 16 * n;
        if (kcol < kN) {
            float* op = out + ((size_t)b * kC + crow) * kN + kcol;
#pragma unroll
            for (int r = 0; r < 4; ++r) op[(size_t)r * kN] = acc[n][r];
        }
    }
}

extern "C" void kernel_launch(void* const* d_in, const int* in_sizes, int n_in,
                              void* d_out, int out_size, void* d_ws, size_t ws_size,
                              hipStream_t stream) {
    const float* q = (const float*)d_in[0];
    const float* k = (const float*)d_in[1];
    const float* v = (const float*)d_in[2];

    float* out  = (float*)d_out;               // [B, C, N]
    float* attn = out + kOutElems;             // [B, N, N]
    float* D1   = (float*)d_ws;                // [B, N, N] second dist half

    const size_t need = kAttnElems * sizeof(float);

    if (ws_size >= need) {
        dist_kernel<true><<<kB * CSP * NKT * NQT, 256, 0, stream>>>(q, k, attn, D1);
        softmax_kernel<true><<<kB * kN, 256, 0, stream>>>(attn, D1);
        bmm_mfma<<<kB * 2 * NKT3, 256, 0, stream>>>(v, attn, out);
    } else {
        // Fallback without workspace: accumulate dist via atomics; MFMA bmm needs no ws.
        hipMemsetAsync(attn, 0, kAttnElems * sizeof(float), stream);
        dist_kernel<false><<<kB * CSP * NKT * NQT, 256, 0, stream>>>(q, k, attn, nullptr);
        softmax_kernel<false><<<kB * kN, 256, 0, stream>>>(attn, attn);
        bmm_mfma<<<kB * 2 * NKT3, 256, 0, stream>>>(v, attn, out);
    }
}

// Round 2
// 94.840 us; speedup vs baseline: 1.1306x; 1.1306x over previous
//
#include <hip/hip_runtime.h>
#include <math.h>

// Problem constants
constexpr int kB = 2;
constexpr int kC = 128;
constexpr int kN = 784;
constexpr float kInvT = 1.0f / 11.313708498984761f;  // 1/sqrt(C)
constexpr float kInvC = 1.0f / 128.0f;

constexpr size_t kOutElems  = (size_t)kB * kC * kN;  // 200704
constexpr size_t kAttnElems = (size_t)kB * kN * kN;  // 1229312

__device__ inline float wave_max(float v) {
#pragma unroll
    for (int o = 32; o > 0; o >>= 1) v = fmaxf(v, __shfl_xor(v, o, 64));
    return v;
}
__device__ inline float wave_sum(float v) {
#pragma unroll
    for (int o = 32; o > 0; o >>= 1) v += __shfl_xor(v, o, 64);
    return v;
}

// ================= Kernel 1: D[b,k,q] = sum_c |q[c,q]/T - k[c,k]| (raw sums) =================
// 64k x 64q tile, 4k x 4q per thread (16 indep accs; VALU:LDS = 64:24 cyc/c-iter),
// c split in 2 halves. LDS 34.8 KB -> 4 blocks/CU resident; grid 2b*2ch*13*13 = 676.
constexpr int TK = 64;
constexpr int TQ = 64;
constexpr int NKT = (kN + TK - 1) / TK;  // 13
constexpr int NQT = (kN + TQ - 1) / TQ;  // 13
constexpr int CSP = 2;
constexpr int CH = kC / CSP;             // 64
constexpr int DSTR = 68;                 // 64+4 pad

template <bool USE_WS>
__global__ __launch_bounds__(256) void dist_kernel(const float* __restrict__ qg,
                                                   const float* __restrict__ kg,
                                                   float* __restrict__ D0,
                                                   float* __restrict__ D1) {
    int bid = blockIdx.x;
    const int qt = bid % NQT; bid /= NQT;
    const int kt = bid % NKT; bid /= NKT;
    const int ch = bid & 1;   bid >>= 1;
    const int b  = bid;
    const int k0 = kt * TK;
    const int q0 = qt * TQ;
    const int t  = threadIdx.x;

    __shared__ float ks[CH][DSTR];  // 17.4 KB
    __shared__ float qs[CH][DSTR];  // 17.4 KB

    const float* kb = kg + ((size_t)b * kC + ch * CH) * kN;
    const float* qb = qg + ((size_t)b * kC + ch * CH) * kN;

#pragma unroll
    for (int i = t; i < CH * 16; i += 256) {
        const int c  = i >> 4;
        const int x4 = (i & 15) << 2;
        *reinterpret_cast<float4*>(&ks[c][x4]) =
            *reinterpret_cast<const float4*>(kb + (size_t)c * kN + min(k0 + x4, kN - 4));
        float4 qv = *reinterpret_cast<const float4*>(qb + (size_t)c * kN + min(q0 + x4, kN - 4));
        qv.x *= kInvT; qv.y *= kInvT; qv.z *= kInvT; qv.w *= kInvT;
        *reinterpret_cast<float4*>(&qs[c][x4]) = qv;
    }
    __syncthreads();

    const int qx = (t & 15) << 2;  // 16 q-groups (b128, 2-way across half-wave = free)
    const int kx = (t >> 4) << 2;  // 16 k-groups (b128, 16-lane broadcast)

    float acc[4][4];
#pragma unroll
    for (int i = 0; i < 4; ++i)
#pragma unroll
        for (int j = 0; j < 4; ++j) acc[i][j] = 0.0f;

#pragma unroll 4
    for (int c = 0; c < CH; ++c) {
        const float4 kv = *reinterpret_cast<const float4*>(&ks[c][kx]);
        const float4 qv = *reinterpret_cast<const float4*>(&qs[c][qx]);
        const float kf[4] = {kv.x, kv.y, kv.z, kv.w};
        const float qf[4] = {qv.x, qv.y, qv.z, qv.w};
#pragma unroll
        for (int i = 0; i < 4; ++i)
#pragma unroll
            for (int j = 0; j < 4; ++j)
                acc[i][j] += fabsf(qf[j] - kf[i]);  // v_sub + v_add(abs) = 2 VALU
    }

    const int qcol = q0 + qx;
    if (qcol < kN) {
        float* dst = (USE_WS && ch) ? D1 : D0;
#pragma unroll
        for (int i = 0; i < 4; ++i) {
            const int krow = k0 + kx + i;
            if (krow < kN) {
                const size_t off = ((size_t)b * kN + krow) * kN + qcol;
                if (USE_WS) {
                    *reinterpret_cast<float4*>(dst + off) =
                        make_float4(acc[i][0], acc[i][1], acc[i][2], acc[i][3]);
                } else {
                    atomicAdd(&D0[off + 0], acc[i][0]);
                    atomicAdd(&D0[off + 1], acc[i][1]);
                    atomicAdd(&D0[off + 2], acc[i][2]);
                    atomicAdd(&D0[off + 3], acc[i][3]);
                }
            }
        }
    }
}

// ================= Kernel 2: row softmax over q (sums the two c-halves) =================
template <bool SUM2>
__global__ __launch_bounds__(256) void softmax_kernel(float* __restrict__ A,
                                                      const float* __restrict__ W) {
    const size_t row = (size_t)blockIdx.x * kN;
    float4* A4 = reinterpret_cast<float4*>(A + row);
    const float4* W4 = reinterpret_cast<const float4*>(W + row);
    const int t = threadIdx.x;
    const int lane = t & 63, wid = t >> 6;
    const bool act = t < (kN / 4);  // 196
    __shared__ float xred[4];

    float4 x = make_float4(-1e30f, -1e30f, -1e30f, -1e30f);
    if (act) {
        x = A4[t];
        if (SUM2) {
            const float4 w = W4[t];
            x.x += w.x; x.y += w.y; x.z += w.z; x.w += w.w;
        }
    }

    float m = fmaxf(fmaxf(x.x, x.y), fmaxf(x.z, x.w));
    m = wave_max(m);
    if (lane == 0) xred[wid] = m;
    __syncthreads();
    m = fmaxf(fmaxf(xred[0], xred[1]), fmaxf(xred[2], xred[3]));
    __syncthreads();

    float4 p;
    p.x = __expf((x.x - m) * kInvC);
    p.y = __expf((x.y - m) * kInvC);
    p.z = __expf((x.z - m) * kInvC);
    p.w = __expf((x.w - m) * kInvC);
    float lsum = p.x + p.y + p.z + p.w;  // inactive: exp(-huge)=0
    lsum = wave_sum(lsum);
    if (lane == 0) xred[wid] = lsum;
    __syncthreads();
    const float inv = 1.0f / (xred[0] + xred[1] + xred[2] + xred[3]);
    if (act) {
        p.x *= inv; p.y *= inv; p.z *= inv; p.w *= inv;
        A4[t] = p;
    }
}

// ================= Kernel 3: MFMA bmm, NO LDS / NO barriers, q-split partials ==========
// out[b,c,k] = sum_q v[b,c,q]*attn[b,k,q];  GEMM per batch: M=128(c), N=784(k), K=784(q).
// Round-1 post-mortem: 52-block LDS version was latency-exposed (1 blk/CU on 52 CUs,
// 2 barriers/chunk, 8-way LDS conflicts). Fix: fragments straight from global (attn/v are
// L2-resident; each frag row = 32B/lane contiguous, quarter-waves tile 128B per row),
// q split 7x128 -> grid 2b*2ct*13kt*7qs = 364 barrier-free blocks (~6 waves/CU).
// Per wave: 16c x 64k tile, 4 ks-steps x {10 dwordx4 loads, cvt_pk to fp16, 4 MFMA}.
// OOB k-rows clamped (junk never stored); tail q-slice predicates loads to zero.
// Fragment map (m89-verified): A row=lane&15, k=(lane>>4)*8+j; B col=lane&15, same k;
// D col=lane&15, row=(lane>>4)*4+reg.
typedef _Float16 half8v __attribute__((ext_vector_type(8)));
typedef float f32x4 __attribute__((ext_vector_type(4)));

constexpr int GN = 64;                    // k cols per block
constexpr int GK = 128;                   // q per slice
constexpr int QSP3 = (kN + GK - 1) / GK;  // 7 (last slice: 16 valid q)
constexpr int NKT3 = (kN + GN - 1) / GN;  // 13

__device__ inline half8v to_h8(const float4 a, const float4 b) {
    half8v h;
    h[0] = (_Float16)a.x; h[1] = (_Float16)a.y; h[2] = (_Float16)a.z; h[3] = (_Float16)a.w;
    h[4] = (_Float16)b.x; h[5] = (_Float16)b.y; h[6] = (_Float16)b.z; h[7] = (_Float16)b.w;
    return h;
}

template <bool ATOMIC>
__global__ __launch_bounds__(256) void bmm_mfma(const float* __restrict__ vg,
                                                const float* __restrict__ attn,
                                                float* __restrict__ P) {
    int bid = blockIdx.x;
    const int qs = bid % QSP3; bid /= QSP3;
    const int kt = bid % NKT3; bid /= NKT3;
    const int ct = bid & 1;    bid >>= 1;
    const int b  = bid;
    const int k0 = kt * GN;
    const int c0 = ct * 64;
    const int q0 = qs * GK;
    const int t  = threadIdx.x;
    const int lane = t & 63;
    const int w = t >> 6;

    const int lrow = lane & 15;           // frag row/col within 16
    const int kgrp = (lane >> 4) * 8;     // q offset of this lane's 8 k-elems

    // Per-lane base pointers (OOB attn rows clamped; junk cols discarded at store).
    const float* vp = vg + (((size_t)b * kC + c0 + 16 * w + lrow) * kN + q0 + kgrp);
    const float* ap[4];
#pragma unroll
    for (int n = 0; n < 4; ++n) {
        const int krow = min(k0 + 16 * n + lrow, kN - 1);
        ap[n] = attn + (((size_t)b * kN + krow) * kN + q0 + kgrp);
    }

    f32x4 acc[4] = {};  // 4 n-frags: wave owns 16 c-rows x 64 k-cols

    if (q0 + GK <= kN) {  // full slice: 4 ks-steps, no predication
#pragma unroll
        for (int ks = 0; ks < GK / 32; ++ks) {
            const int qb = ks * 32;
            const half8v av = to_h8(*reinterpret_cast<const float4*>(vp + qb),
                                    *reinterpret_cast<const float4*>(vp + qb + 4));
#pragma unroll
            for (int n = 0; n < 4; ++n) {
                const half8v bv = to_h8(*reinterpret_cast<const float4*>(ap[n] + qb),
                                        *reinterpret_cast<const float4*>(ap[n] + qb + 4));
                acc[n] = __builtin_amdgcn_mfma_f32_16x16x32_f16(av, bv, acc[n], 0, 0, 0);
            }
        }
    } else {  // tail slice (qs==6): only ks=0 has data; predicate lanes past kN
        const float4 z = make_float4(0.f, 0.f, 0.f, 0.f);
        const bool ok = (q0 + kgrp) < kN;  // spans of 8 never straddle kN (784%16==0)
        const half8v av = to_h8(ok ? *reinterpret_cast<const float4*>(vp) : z,
                                ok ? *reinterpret_cast<const float4*>(vp + 4) : z);
#pragma unroll
        for (int n = 0; n < 4; ++n) {
            const half8v bv = to_h8(ok ? *reinterpret_cast<const float4*>(ap[n]) : z,
                                    ok ? *reinterpret_cast<const float4*>(ap[n] + 4) : z);
            acc[n] = __builtin_amdgcn_mfma_f32_16x16x32_f16(av, bv, acc[n], 0, 0, 0);
        }
    }

    // Epilogue: D col=lane&15, row=(lane>>4)*4+r. Store partial slice (or atomicAdd).
    const int crow = c0 + 16 * w + (lane >> 4) * 4;
    const int kc = k0 + lrow;
#pragma unroll
    for (int n = 0; n < 4; ++n) {
        const int kcol = kc + 16 * n;
        if (kcol < kN) {
            if (ATOMIC) {
#pragma unroll
                for (int r = 0; r < 4; ++r)
                    atomicAdd(&P[((size_t)b * kC + crow + r) * kN + kcol], acc[n][r]);
            } else {
                float* op = P + (((size_t)qs * kB + b) * kC + crow) * kN + kcol;
#pragma unroll
                for (int r = 0; r < 4; ++r) op[(size_t)r * kN] = acc[n][r];
            }
        }
    }
}

// ================= Kernel 4: out = sum_qs partial[qs] =================
// 196 blocks x 256 threads; one float4 per thread; slices L2/L3-resident.
__global__ __launch_bounds__(256) void reduce_kernel(const float* __restrict__ P,
                                                     float* __restrict__ out) {
    const int idx = blockIdx.x * 256 + threadIdx.x;  // < 50176 exactly
    const float4* p = reinterpret_cast<const float4*>(P) + idx;
    float4 s = p[0];
#pragma unroll
    for (int qs = 1; qs < QSP3; ++qs) {
        const float4 v = p[(size_t)qs * (kOutElems / 4)];
        s.x += v.x; s.y += v.y; s.z += v.z; s.w += v.w;
    }
    reinterpret_cast<float4*>(out)[idx] = s;
}

extern "C" void kernel_launch(void* const* d_in, const int* in_sizes, int n_in,
                              void* d_out, int out_size, void* d_ws, size_t ws_size,
                              hipStream_t stream) {
    const float* q = (const float*)d_in[0];
    const float* k = (const float*)d_in[1];
    const float* v = (const float*)d_in[2];

    float* out  = (float*)d_out;               // [B, C, N]
    float* attn = out + kOutElems;             // [B, N, N]
    float* D1   = (float*)d_ws;                // [B, N, N] second dist half
    float* P    = D1 + kAttnElems;             // [QSP3][B, C, N] partials

    const size_t need = (kAttnElems + (size_t)QSP3 * kOutElems) * sizeof(float);

    if (ws_size >= need) {
        dist_kernel<true><<<kB * CSP * NKT * NQT, 256, 0, stream>>>(q, k, attn, D1);
        softmax_kernel<true><<<kB * kN, 256, 0, stream>>>(attn, D1);
        bmm_mfma<false><<<kB * 2 * NKT3 * QSP3, 256, 0, stream>>>(v, attn, P);
        reduce_kernel<<<(int)(kOutElems / 4 / 256), 256, 0, stream>>>(P, out);
    } else {
        // Fallback without workspace: accumulate via atomics.
        hipMemsetAsync(attn, 0, kAttnElems * sizeof(float), stream);
        hipMemsetAsync(out, 0, kOutElems * sizeof(float), stream);
        dist_kernel<false><<<kB * CSP * NKT * NQT, 256, 0, stream>>>(q, k, attn, nullptr);
        softmax_kernel<false><<<kB * kN, 256, 0, stream>>>(attn, attn);
        bmm_mfma<true><<<kB * 2 * NKT3 * QSP3, 256, 0, stream>>>(v, attn, out);
    }
}